// Round 20
// baseline (231.283 us; speedup 1.0000x reference)
//
#include <hip/hip_runtime.h>
#include <hip/hip_bf16.h>
#include <math.h>

// Problem constants
#define BB 2
#define SS 2048
#define DD 1024
#define HH 16
#define DH 64
#define NROW (BB*SS)          // 4096
#define FFN (4*DD)            // 4096

typedef __attribute__((ext_vector_type(8))) __bf16 bf16x8;
typedef __attribute__((ext_vector_type(4))) __bf16 bf16x4;
typedef __attribute__((ext_vector_type(4))) float f32x4;

// Q pre-scale: 1/sqrt(64) * log2(e)  (softmax runs in exp2 domain)
#define QSCALE 0.18033688011112042f
// finite "empty" max: avoids (-inf) - (-inf) = NaN for fully-masked partials
#define NEG_BIG (-3.0e38f)

__device__ __forceinline__ ushort f2b(float f) {
    union { float f; uint32_t u; } x; x.f = f;
    uint32_t r = x.u + 0x7FFF + ((x.u >> 16) & 1);
    return (ushort)(r >> 16);
}
__device__ __forceinline__ float b2f(ushort u) {
    union { uint32_t u; float f; } x; x.u = (uint32_t)u << 16;
    return x.f;
}

// ---------------- LayerNorm (torch semantics: ddof=1, eps on std) -> bf16 ----
__global__ __launch_bounds__(256)
void ln_kernel(const float* __restrict__ x, const float* __restrict__ scale,
               const float* __restrict__ shift, ushort* __restrict__ y) {
    int row = blockIdx.x;
    const float* xr = x + (size_t)row * DD;
    ushort* yr = y + (size_t)row * DD;
    int t = threadIdx.x;
    float v[4];
    float s = 0.f, ss = 0.f;
#pragma unroll
    for (int i = 0; i < 4; ++i) {
        v[i] = xr[t + 256 * i];
        s += v[i];
        ss += v[i] * v[i];
    }
#pragma unroll
    for (int off = 32; off; off >>= 1) {
        s  += __shfl_xor(s, off);
        ss += __shfl_xor(ss, off);
    }
    __shared__ float red[8];
    int w = t >> 6;
    if ((t & 63) == 0) { red[w] = s; red[w + 4] = ss; }
    __syncthreads();
    float st  = red[0] + red[1] + red[2] + red[3];
    float sst = red[4] + red[5] + red[6] + red[7];
    float mu = st * (1.f / DD);
    float var = (sst - DD * mu * mu) * (1.f / (DD - 1));
    var = fmaxf(var, 0.f);
    float inv = 1.f / (sqrtf(var) + 1e-9f);
#pragma unroll
    for (int i = 0; i < 4; ++i) {
        int c = t + 256 * i;
        yr[c] = f2b(scale[c] * (v[i] - mu) * inv + shift[c]);
    }
}

// Fused: proj = sum_z pw_z + bo;  o2 = bf16(LN(proj + input))
__global__ __launch_bounds__(256)
void ln_res4_kernel(const ushort* __restrict__ p, const float* __restrict__ pbias,
                    const float* __restrict__ xb,
                    const float* __restrict__ scale, const float* __restrict__ shift,
                    ushort* __restrict__ yb) {
    const size_t MN = (size_t)NROW * DD;
    int row = blockIdx.x;
    ushort* ybr = yb + (size_t)row * DD;
    int t = threadIdx.x;
    float v[4];
    float s = 0.f, ss = 0.f;
#pragma unroll
    for (int i = 0; i < 4; ++i) {
        int c = t + 256 * i;
        size_t idx = (size_t)row * DD + c;
        float sum = b2f(p[idx]) + b2f(p[MN + idx]) + b2f(p[2 * MN + idx])
                  + b2f(p[3 * MN + idx]) + pbias[c] + xb[idx];
        v[i] = sum;
        s += sum;
        ss += sum * sum;
    }
#pragma unroll
    for (int off = 32; off; off >>= 1) {
        s  += __shfl_xor(s, off);
        ss += __shfl_xor(ss, off);
    }
    __shared__ float red[8];
    int w = t >> 6;
    if ((t & 63) == 0) { red[w] = s; red[w + 4] = ss; }
    __syncthreads();
    float st  = red[0] + red[1] + red[2] + red[3];
    float sst = red[4] + red[5] + red[6] + red[7];
    float mu = st * (1.f / DD);
    float var = (sst - DD * mu * mu) * (1.f / (DD - 1));
    var = fmaxf(var, 0.f);
    float inv = 1.f / (sqrtf(var) + 1e-9f);
#pragma unroll
    for (int i = 0; i < 4; ++i) {
        int c = t + 256 * i;
        ybr[c] = f2b(scale[c] * (v[i] - mu) * inv + shift[c]);
    }
}

// ---------------- fp32 -> bf16 transpose-convert for weights -----------------
__global__ __launch_bounds__(256)
void transpose_bf16_kernel(const float* __restrict__ W, ushort* __restrict__ Wt,
                           int K, int N) {
    __shared__ ushort tile[32][33];
    int tx = threadIdx.x & 31;
    int ty = threadIdx.x >> 5;      // 0..7
    int n0 = blockIdx.x * 32;
    int k0 = blockIdx.y * 32;
#pragma unroll
    for (int i = 0; i < 32; i += 8)
        tile[ty + i][tx] = f2b(W[(size_t)(k0 + ty + i) * N + n0 + tx]);
    __syncthreads();
#pragma unroll
    for (int i = 0; i < 32; i += 8)
        Wt[(size_t)(n0 + ty + i) * K + k0 + tx] = tile[tx][ty + i];
}

// fused 4x 1024x1024 transpose (z selects Wq/Wk/Wv/Wo; dst slabs contiguous)
__global__ __launch_bounds__(256)
void transpose4_bf16_kernel(const float* __restrict__ W0, const float* __restrict__ W1,
                            const float* __restrict__ W2, const float* __restrict__ W3,
                            ushort* __restrict__ Wt) {
    __shared__ ushort tile[32][33];
    int z = blockIdx.z;
    const float* W = z == 0 ? W0 : (z == 1 ? W1 : (z == 2 ? W2 : W3));
    ushort* dst = Wt + (size_t)z * DD * DD;
    int tx = threadIdx.x & 31;
    int ty = threadIdx.x >> 5;      // 0..7
    int n0 = blockIdx.x * 32;
    int k0 = blockIdx.y * 32;
#pragma unroll
    for (int i = 0; i < 32; i += 8)
        tile[ty + i][tx] = f2b(W[(size_t)(k0 + ty + i) * DD + n0 + tx]);
    __syncthreads();
#pragma unroll
    for (int i = 0; i < 32; i += 8)
        dst[(size_t)(n0 + ty + i) * DD + k0 + tx] = tile[tx][ty + i];
}

// ---------------- FFN2 reduce (4-way bf16 partials + residual) ---------------
__global__ __launch_bounds__(256)
void reduce_ffn2_kernel(const ushort* __restrict__ p, const float* __restrict__ bias,
                        const ushort* __restrict__ res, float* __restrict__ out) {
    const size_t MN = (size_t)NROW * DD;
    int i = (blockIdx.x * 256 + threadIdx.x) * 4;
    ushort4 a = *reinterpret_cast<const ushort4*>(p + i);
    ushort4 b = *reinterpret_cast<const ushort4*>(p + MN + i);
    ushort4 c4 = *reinterpret_cast<const ushort4*>(p + 2 * MN + i);
    ushort4 d4 = *reinterpret_cast<const ushort4*>(p + 3 * MN + i);
    ushort4 r = *reinterpret_cast<const ushort4*>(res + i);
    int c = i & (DD - 1);
    float4 bs = *reinterpret_cast<const float4*>(bias + c);
    float4 o;
    o.x = b2f(a.x) + b2f(b.x) + b2f(c4.x) + b2f(d4.x) + bs.x + b2f(r.x);
    o.y = b2f(a.y) + b2f(b.y) + b2f(c4.y) + b2f(d4.y) + bs.y + b2f(r.y);
    o.z = b2f(a.z) + b2f(b.z) + b2f(c4.z) + b2f(d4.z) + bs.z + b2f(r.z);
    o.w = b2f(a.w) + b2f(b.w) + b2f(c4.w) + b2f(d4.w) + bs.w + b2f(r.w);
    *reinterpret_cast<float4*>(out + i) = o;
}

// ---------------- attention split-K combine ----------------------------------
// O = (O0*w0 + O1*w1) / (l0*w0 + l1*w1), w_z = exp2(m_z - max(m0,m1))
__global__ __launch_bounds__(256)
void attn_combine_kernel(const ushort* __restrict__ po, const float2* __restrict__ ml,
                         ushort* __restrict__ att) {
    const size_t MN = (size_t)NROW * DD;
    int i = blockIdx.x * 256 + threadIdx.x;   // float4-granule index
    int e = i * 4;
    int d0 = e & (DD - 1);
    int s = (e >> 10) & (SS - 1);
    int b = e >> 21;
    int h = d0 >> 6;
    int bh = b * HH + h;
    float2 ml0 = ml[(size_t)bh * SS + s];
    float2 ml1 = ml[(size_t)(BB * HH) * SS + (size_t)bh * SS + s];
    float M = fmaxf(ml0.x, ml1.x);
    float w0 = __builtin_amdgcn_exp2f(ml0.x - M);
    float w1 = __builtin_amdgcn_exp2f(ml1.x - M);
    float inv = 1.f / (ml0.y * w0 + ml1.y * w1);
    ushort4 a = *reinterpret_cast<const ushort4*>(po + e);
    ushort4 c = *reinterpret_cast<const ushort4*>(po + MN + e);
    ushort4 o;
    o.x = f2b((b2f(a.x) * w0 + b2f(c.x) * w1) * inv);
    o.y = f2b((b2f(a.y) * w0 + b2f(c.y) * w1) * inv);
    o.z = f2b((b2f(a.z) * w0 + b2f(c.z) * w1) * inv);
    o.w = f2b((b2f(a.w) * w0 + b2f(c.w) * w1) * inv);
    *reinterpret_cast<ushort4*>(att + e) = o;
}

// ---------------- bf16 MFMA GEMM: 8 waves, DEPTH ring, BM=128 x BN tile ------
#define GBM 128
#define GBK 32

template <int MODE, bool BF16_OUT, int DEPTH, int BN>
__global__ __launch_bounds__(512)
void gemm_bf16_kernel(const ushort* __restrict__ A, const ushort* __restrict__ Wt,
                      const float* __restrict__ bias, const ushort* __restrict__ addsrc,
                      void* __restrict__ Cout, int M, int N, int K, int lda,
                      const float* __restrict__ bias2, const float* __restrict__ bias3,
                      void* __restrict__ out2, void* __restrict__ out3) {
    __shared__ ushort As[DEPTH][GBM * GBK];   // DEPTH x 8KB
    __shared__ ushort Bs[DEPTH][BN * GBK];    // DEPTH x BN/128 x 8KB
    constexpr int NF = BN / 64;               // B-frags per wave (2 or 4)

    int tid = threadIdx.x;
    int lane = tid & 63;
    int wid = tid >> 6;              // 0..7
    int wr = wid >> 2, wc = wid & 3; // 2 x 4 wave grid

    int gx = gridDim.x;
    int nwg = gx * gridDim.y;
    int orig = blockIdx.y * gx + blockIdx.x;
    int q8 = nwg >> 3;
    int swz = (orig & 7) * q8 + (orig >> 3);
    int bx = swz % gx, by = swz / gx;

    int brow = by * GBM;
    int bcol = bx * BN;
    size_t koff = (size_t)blockIdx.z * K;

    int lrow = lane & 15;
    int kgrp = lane >> 4;

    f32x4 acc[4][NF] = {};

    auto stage = [&](int buf, int k0) {
        {
            int row = tid >> 2;
            int gran = (tid & 3) ^ ((row >> 1) & 3);
            const char* ga = (const char*)A +
                ((size_t)(brow + row) * lda + koff + k0) * 2 + gran * 16;
            __builtin_amdgcn_global_load_lds(
                (const __attribute__((address_space(1))) uint32_t*)ga,
                (__attribute__((address_space(3))) uint32_t*)(&As[buf][0] + (wid * 16) * GBK),
                16, 0, 0);
        }
#pragma unroll
        for (int i = 0; i < BN / 128; ++i) {
            int idx = i * 512 + tid;
            int row = idx >> 2;
            int gran = (idx & 3) ^ ((row >> 1) & 3);
            const char* gb = (const char*)Wt +
                ((size_t)(bcol + row) * lda + koff + k0) * 2 + gran * 16;
            __builtin_amdgcn_global_load_lds(
                (const __attribute__((address_space(1))) uint32_t*)gb,
                (__attribute__((address_space(3))) uint32_t*)(&Bs[buf][0] + (i * 128 + wid * 16) * GBK),
                16, 0, 0);
        }
    };

    int nk = K / GBK;
    constexpr int PRE = DEPTH - 1;
#pragma unroll
    for (int s = 0; s < PRE; ++s)
        if (s < nk) stage(s, s * GBK);

    int cur = 0, stg = PRE;
    for (int t = 0; t < nk; ++t) {
        __builtin_amdgcn_sched_barrier(0);
        int rem = nk - 1 - t;
        if constexpr (DEPTH == 3 && BN == 128) {
            if (rem >= 1)      asm volatile("s_waitcnt vmcnt(2)" ::: "memory");
            else               asm volatile("s_waitcnt vmcnt(0)" ::: "memory");
        } else if constexpr (DEPTH == 3 && BN == 256) {
            if (rem >= 1)      asm volatile("s_waitcnt vmcnt(3)" ::: "memory");
            else               asm volatile("s_waitcnt vmcnt(0)" ::: "memory");
        } else {
            asm volatile("s_waitcnt vmcnt(0)" ::: "memory");
        }
        asm volatile("s_barrier" ::: "memory");
        if (t + PRE < nk) stage(stg, (t + PRE) * GBK);

        bf16x8 afrag[4], bfrag[NF];
#pragma unroll
        for (int mi = 0; mi < 4; ++mi) {
            int row = wr * 64 + mi * 16 + lrow;
            int gran = kgrp ^ ((row >> 1) & 3);
            afrag[mi] = *(const bf16x8*)((const char*)&As[cur][0] + row * 64 + gran * 16);
        }
#pragma unroll
        for (int ni = 0; ni < NF; ++ni) {
            int row = wc * (BN / 4) + ni * 16 + lrow;
            int gran = kgrp ^ ((row >> 1) & 3);
            bfrag[ni] = *(const bf16x8*)((const char*)&Bs[cur][0] + row * 64 + gran * 16);
        }
#pragma unroll
        for (int mi = 0; mi < 4; ++mi)
#pragma unroll
            for (int ni = 0; ni < NF; ++ni)
                acc[mi][ni] = __builtin_amdgcn_mfma_f32_16x16x32_bf16(
                    afrag[mi], bfrag[ni], acc[mi][ni], 0, 0, 0);

        cur = (cur == DEPTH - 1) ? 0 : cur + 1;
        stg = (stg == DEPTH - 1) ? 0 : stg + 1;
    }

    if (MODE == 3) {
        int which = bcol >> 10;
        const float* bs = which == 0 ? bias : (which == 1 ? bias2 : bias3);
#pragma unroll
        for (int ni = 0; ni < NF; ++ni) {
            int col = bcol + wc * (BN / 4) + ni * 16 + lrow;
            int lcol = col & 1023;
            float bsv = bs[lcol];
#pragma unroll
            for (int mi = 0; mi < 4; ++mi) {
                f32x4 a = acc[mi][ni];
#pragma unroll
                for (int j = 0; j < 4; ++j) {
                    int row = brow + wr * 64 + mi * 16 + kgrp * 4 + j;
                    float val = a[j] + bsv;
                    if (which == 2) {
                        size_t idx = (size_t)(row >> 11) * ((size_t)DD * SS)
                                   + (size_t)lcol * SS + (row & (SS - 1));
                        ((ushort*)out3)[idx] = f2b(val);
                    } else if (which == 0) {
                        ((ushort*)Cout)[(size_t)row * DD + lcol] = f2b(val * QSCALE);
                    } else {
                        ((ushort*)out2)[(size_t)row * DD + lcol] = f2b(val);
                    }
                }
            }
        }
        return;
    }

    if (MODE == 4) {
        ushort* dst = (ushort*)Cout + (size_t)blockIdx.z * ((size_t)M * N);
#pragma unroll
        for (int ni = 0; ni < NF; ++ni) {
            int col = bcol + wc * (BN / 4) + ni * 16 + lrow;
#pragma unroll
            for (int mi = 0; mi < 4; ++mi) {
                f32x4 a = acc[mi][ni];
#pragma unroll
                for (int j = 0; j < 4; ++j) {
                    int row = brow + wr * 64 + mi * 16 + kgrp * 4 + j;
                    dst[(size_t)row * N + col] = f2b(a[j]);
                }
            }
        }
        return;
    }

#pragma unroll
    for (int ni = 0; ni < NF; ++ni) {
        int col = bcol + wc * (BN / 4) + ni * 16 + lrow;
        float bsv = bias[col];
#pragma unroll
        for (int mi = 0; mi < 4; ++mi) {
            f32x4 a = acc[mi][ni];
#pragma unroll
            for (int j = 0; j < 4; ++j) {
                int row = brow + wr * 64 + mi * 16 + kgrp * 4 + j;
                float val = a[j] + bsv;
                if (MODE == 1) val = fmaxf(val, 0.f);
                if (BF16_OUT)
                    ((ushort*)Cout)[(size_t)row * N + col] = f2b(val);
                else
                    ((float*)Cout)[(size_t)row * N + col] = val;
            }
        }
    }
}

// ---------------- bf16 MFMA causal flash attention (split-K over keys) -------
// Grid (bh, pair, z=2). Block z handles k-tiles [z*(pr+1), (z+1)*(pr+1)) of
// q-pair pr (nt = 2pr+2 total -> equal halves; z1 contains the diagonal).
// Writes unnormalized O partials (bf16) + per-q-row (m, l); combine merges.
// m init = NEG_BIG (finite) so fully-masked rows yield p=0, l=0 (no NaN).
__global__ __launch_bounds__(512)
void attn_mfma_kernel(const ushort* __restrict__ Qg, const ushort* __restrict__ Kg,
                      const ushort* __restrict__ Vtg, ushort* __restrict__ Po,
                      float2* __restrict__ Ml) {
    __shared__ ushort Qs[128 * 64];       // 16KB; reused as Ps after Q hoist
    __shared__ ushort Ks[2][64 * 64];     // 16KB
    __shared__ ushort Vs[2][64 * 64];     // 16KB

    int tid = threadIdx.x;
    int lane = tid & 63;
    int wid = tid >> 6;              // 0..7
    int bh = blockIdx.x;
    int b = bh >> 4, h = bh & 15;
    int pr = blockIdx.y;             // 0..15
    int z = blockIdx.z;              // 0..1 (key-range half)
    int qp0 = pr * 128;
    int half = pr + 1;               // k-tiles per half
    int t0 = z * half;

    const ushort* Qbase = Qg + ((size_t)(b * SS + qp0)) * DD + h * DH;
    const ushort* Kbase = Kg + ((size_t)(b * SS)) * DD + h * DH;
    const ushort* Vbase = Vtg + (size_t)bh * DH * SS;

    int g = lane >> 4;
    int lr = lane & 15;

    auto stageKV = [&](int buf, int k0) {
        int rr = wid * 8 + (lane >> 3);
        int gg = (lane & 7) ^ (rr & 7);
        const ushort* srck = Kbase + (size_t)(k0 + rr) * DD + gg * 8;
        __builtin_amdgcn_global_load_lds(
            (const __attribute__((address_space(1))) uint32_t*)srck,
            (__attribute__((address_space(3))) uint32_t*)(&Ks[buf][0] + (wid * 8) * 64),
            16, 0, 0);
        const ushort* srcv = Vbase + (size_t)rr * SS + k0 + gg * 8;
        __builtin_amdgcn_global_load_lds(
            (const __attribute__((address_space(1))) uint32_t*)srcv,
            (__attribute__((address_space(3))) uint32_t*)(&Vs[buf][0] + (wid * 8) * 64),
            16, 0, 0);
    };

    {
        int rr0 = wid * 16 + (lane >> 3);
        int g0 = lane & 7;
#pragma unroll
        for (int i = 0; i < 2; ++i) {
            int rr = rr0 + i * 8;
            int gg = g0 ^ (rr & 7);
            const ushort* src = Qbase + (size_t)rr * DD + gg * 8;
            __builtin_amdgcn_global_load_lds(
                (const __attribute__((address_space(1))) uint32_t*)src,
                (__attribute__((address_space(3))) uint32_t*)(Qs + (wid * 16 + i * 8) * 64),
                16, 0, 0);
        }
    }
    stageKV(0, t0 * 64);
    asm volatile("s_waitcnt vmcnt(2)" ::: "memory");

    int offF[8];
#pragma unroll
    for (int ni = 0; ni < 4; ++ni)
#pragma unroll
        for (int ks = 0; ks < 2; ++ks) {
            int r = ni * 16 + lr;
            offF[ni * 2 + ks] = r * 128 + (((ks * 4 + g) ^ (r & 7)) << 4);
        }
    int rq = wid * 16 + lr;
    int offQ[2];
#pragma unroll
    for (int ks = 0; ks < 2; ++ks)
        offQ[ks] = rq * 128 + (((ks * 4 + g) ^ (rq & 7)) << 4);
    int offPw[4];
#pragma unroll
    for (int ni = 0; ni < 4; ++ni)
        offPw[ni] = rq * 128 + (((ni * 2 + (g >> 1)) ^ (rq & 7)) << 4) + (g & 1) * 8;

    bf16x8 aq[2];
#pragma unroll
    for (int ks = 0; ks < 2; ++ks)
        aq[ks] = *(const bf16x8*)((const char*)Qs + offQ[ks]);
    ushort* Ps = Qs;

    f32x4 oacc[4] = {};
    float m = NEG_BIG, l = 0.f;
    const float THR = 11.0f;
    int qa = qp0 + wid * 16 + lr;
    int qw0 = qp0 + wid * 16;

    int cur = 0;
    for (int tt = 0; tt < half; ++tt) {
        int t = t0 + tt;
        __builtin_amdgcn_sched_barrier(0);
        asm volatile("s_waitcnt vmcnt(0)" ::: "memory");
        asm volatile("s_barrier" ::: "memory");
        if (tt + 1 < half) stageKV(cur ^ 1, (t + 1) * 64);
        int k0 = t * 64;

        f32x4 sacc[4] = {};
        __builtin_amdgcn_s_setprio(1);
#pragma unroll
        for (int ni = 0; ni < 4; ++ni)
#pragma unroll
            for (int ks = 0; ks < 2; ++ks) {
                bf16x8 bk = *(const bf16x8*)((const char*)&Ks[cur][0] + offF[ni * 2 + ks]);
                sacc[ni] = __builtin_amdgcn_mfma_f32_16x16x32_bf16(bk, aq[ks], sacc[ni], 0, 0, 0);
            }
        __builtin_amdgcn_s_setprio(0);

        if (k0 + 63 > qw0) {
#pragma unroll
            for (int ni = 0; ni < 4; ++ni) {
#pragma unroll
                for (int j = 0; j < 4; ++j) {
                    int key = k0 + ni * 16 + g * 4 + j;
                    if (key > qa) sacc[ni][j] = -INFINITY;
                }
            }
        }

        float mx = sacc[0][0];
#pragma unroll
        for (int ni = 0; ni < 4; ++ni)
#pragma unroll
            for (int j = 0; j < 4; ++j) mx = fmaxf(mx, sacc[ni][j]);
        mx = fmaxf(mx, __shfl_xor(mx, 16));
        mx = fmaxf(mx, __shfl_xor(mx, 32));

        if (__any(mx > m + THR)) {
            float mn = fmaxf(m, mx);
            float corr = __builtin_amdgcn_exp2f(m - mn);
            m = mn;
            l *= corr;
            float cj[4];
#pragma unroll
            for (int j = 0; j < 4; ++j)
                cj[j] = __shfl(corr, (lane & 48) | (g * 4 + j));
#pragma unroll
            for (int ni = 0; ni < 4; ++ni)
#pragma unroll
                for (int j = 0; j < 4; ++j) oacc[ni][j] *= cj[j];
        }

        float p[4][4];
        float rs = 0.f;
#pragma unroll
        for (int ni = 0; ni < 4; ++ni)
#pragma unroll
            for (int j = 0; j < 4; ++j) {
                p[ni][j] = __builtin_amdgcn_exp2f(sacc[ni][j] - m);
                rs += p[ni][j];
            }
        rs += __shfl_xor(rs, 16);
        rs += __shfl_xor(rs, 32);
        l += rs;

#pragma unroll
        for (int ni = 0; ni < 4; ++ni) {
            bf16x4 w4 = { (__bf16)p[ni][0], (__bf16)p[ni][1],
                          (__bf16)p[ni][2], (__bf16)p[ni][3] };
            *(bf16x4*)((char*)Ps + offPw[ni]) = w4;
        }
        asm volatile("s_waitcnt lgkmcnt(0)" ::: "memory");

        bf16x8 ap[2];
#pragma unroll
        for (int ks = 0; ks < 2; ++ks)
            ap[ks] = *(const bf16x8*)((const char*)Ps + offQ[ks]);
        __builtin_amdgcn_s_setprio(1);
#pragma unroll
        for (int ni = 0; ni < 4; ++ni)
#pragma unroll
            for (int ks = 0; ks < 2; ++ks) {
                bf16x8 bv = *(const bf16x8*)((const char*)&Vs[cur][0] + offF[ni * 2 + ks]);
                oacc[ni] = __builtin_amdgcn_mfma_f32_16x16x32_bf16(ap[ks], bv, oacc[ni], 0, 0, 0);
            }
        __builtin_amdgcn_s_setprio(0);
        cur ^= 1;
    }

    // ---- partial epilogue: unnormalized O (bf16) + per-row (m, l) ----
    {
        const size_t MN = (size_t)NROW * DD;
        ushort* po = Po + (size_t)z * MN;
#pragma unroll
        for (int j = 0; j < 4; ++j) {
            int gr = qp0 + wid * 16 + g * 4 + j;
#pragma unroll
            for (int ni = 0; ni < 4; ++ni) {
                int d = ni * 16 + lr;
                po[((size_t)(b * SS + gr)) * DD + h * DH + d] = f2b(oacc[ni][j]);
            }
        }
        if (g == 0)   // lane lr holds (m,l) for q-row qa (replicated over g)
            Ml[(size_t)z * ((size_t)BB * HH * SS) + (size_t)bh * SS + qa] =
                make_float2(m, l);
    }
}

// ---------------- Launch ------------------------------------------------------
extern "C" void kernel_launch(void* const* d_in, const int* in_sizes, int n_in,
                              void* d_out, int out_size, void* d_ws, size_t ws_size,
                              hipStream_t stream) {
    const float* inputs    = (const float*)d_in[0];
    const float* ln1_scale = (const float*)d_in[1];
    const float* ln1_shift = (const float*)d_in[2];
    const float* Wq = (const float*)d_in[3];
    const float* bq = (const float*)d_in[4];
    const float* Wk = (const float*)d_in[5];
    const float* bk = (const float*)d_in[6];
    const float* Wv = (const float*)d_in[7];
    const float* bv = (const float*)d_in[8];
    const float* Wo = (const float*)d_in[9];
    const float* bo = (const float*)d_in[10];
    const float* W1 = (const float*)d_in[11];
    const float* b1 = (const float*)d_in[12];
    const float* W2 = (const float*)d_in[13];
    const float* b2 = (const float*)d_in[14];
    const float* ln2_scale = (const float*)d_in[15];
    const float* ln2_shift = (const float*)d_in[16];
    float* out = (float*)d_out;

    const size_t MB = 1024 * 1024;
    char* w = (char*)d_ws;
    ushort* q_b   = (ushort*)(w + 0 * MB);     // 8MB (dead after attn)
    ushort* k_b   = (ushort*)(w + 8 * MB);     // 8MB (dead after attn)
    ushort* vt_b  = (ushort*)(w + 16 * MB);    // 8MB (dead after attn)
    ushort* att_b = (ushort*)(w + 24 * MB);    // 8MB (dead after Wo GEMM)
    ushort* po_b  = (ushort*)(w + 32 * MB);    // 16MB attn O partials (32-48)
    float2* ml_b  = (float2*)(w + 48 * MB);    // 1MB attn (m,l) (48-49)
    ushort* pw    = (ushort*)(w + 32 * MB);    // 32MB Wo split-4 partials (after combine)
    ushort* o2_b  = (ushort*)(w + 8 * MB);     // 8MB (over k_b)
    ushort* pf    = (ushort*)(w + 16 * MB);    // 32MB FFN2 split-4 partials (16-48)
    ushort* h1_b  = (ushort*)(w + 64 * MB);    // 32MB
    ushort* wq_t  = (ushort*)(w + 96 * MB);    // 2MB (q/k/v/o contiguous slabs)
    ushort* wk_t  = (ushort*)(w + 98 * MB);
    ushort* wv_t  = (ushort*)(w + 100 * MB);
    ushort* wo_t  = (ushort*)(w + 102 * MB);
    ushort* w1_t  = (ushort*)(w + 104 * MB);   // 8MB
    ushort* w2_t  = (ushort*)(w + 112 * MB);   // 8MB
    ushort* xn_b  = (ushort*)(w + 120 * MB);   // 8MB

    // 0. weight convert+transpose
    transpose4_bf16_kernel<<<dim3(DD / 32, DD / 32, 4), 256, 0, stream>>>(
        Wq, Wk, Wv, Wo, wq_t);
    transpose_bf16_kernel<<<dim3(FFN / 32, DD / 32), 256, 0, stream>>>(W1, w1_t, DD, FFN);
    transpose_bf16_kernel<<<dim3(DD / 32, FFN / 32), 256, 0, stream>>>(W2, w2_t, FFN, DD);

    // 1. LN1 -> bf16
    ln_kernel<<<NROW, 256, 0, stream>>>(inputs, ln1_scale, ln1_shift, xn_b);

    // 2. Fused QKV projection (N=3072; V transposed per head; q pre-scaled).
    dim3 gqkv(3 * DD / 128, NROW / GBM, 1);   // 24 x 32
    gemm_bf16_kernel<3, true, 3, 128><<<gqkv, 512, 0, stream>>>(
        xn_b, wq_t, bq, nullptr, q_b, NROW, 3 * DD, DD, DD, bk, bv, k_b, vt_b);

    // 3. MFMA flash attention, split-K over keys -> partials; then combine.
    dim3 ga(BB * HH, SS / 128, 2);            // 32 x 16 x 2 = 1024 blocks
    attn_mfma_kernel<<<ga, 512, 0, stream>>>(q_b, k_b, vt_b, po_b, ml_b);
    attn_combine_kernel<<<(NROW * DD / 4) / 256, 256, 0, stream>>>(po_b, ml_b, att_b);

    // 4. Output projection, split-K=4, BN=256 -> bf16 partials pw.
    dim3 gwo(DD / 256, NROW / GBM, 4);        // 4 x 32 x 4
    gemm_bf16_kernel<4, false, 3, 256><<<gwo, 512, 0, stream>>>(
        att_b, wo_t, nullptr, nullptr, pw, NROW, DD, DD / 4, DD, nullptr, nullptr, nullptr, nullptr);

    // 5. fused reduce(pw)+bias -> +input -> LN2 -> o2 (bf16)
    ln_res4_kernel<<<NROW, 256, 0, stream>>>(pw, bo, inputs, ln2_scale, ln2_shift, o2_b);

    // 6. FFN up + relu -> h1 (bf16). BN=256: 512 blocks at 72KB = 2/CU round.
    dim3 g2(FFN / 256, NROW / GBM, 1);        // 16 x 32
    gemm_bf16_kernel<1, true, 3, 256><<<g2, 512, 0, stream>>>(
        o2_b, w1_t, b1, nullptr, h1_b, NROW, FFN, DD, DD, nullptr, nullptr, nullptr, nullptr);

    // 7. FFN down, split-K=4, BN=256 -> bf16 partials pf. 512 blocks = round.
    dim3 gf2(DD / 256, NROW / GBM, 4);        // 4 x 32 x 4
    gemm_bf16_kernel<4, false, 3, 256><<<gf2, 512, 0, stream>>>(
        h1_b, w2_t, nullptr, nullptr, pf, NROW, DD, FFN / 4, FFN, nullptr, nullptr, nullptr, nullptr);
    reduce_ffn2_kernel<<<(NROW * DD / 4) / 256, 256, 0, stream>>>(pf, b2, o2_b, out);
}

// Round 21
// 228.451 us; speedup vs baseline: 1.0124x; 1.0124x over previous
//
#include <hip/hip_runtime.h>
#include <hip/hip_bf16.h>
#include <math.h>

// Problem constants
#define BB 2
#define SS 2048
#define DD 1024
#define HH 16
#define DH 64
#define NROW (BB*SS)          // 4096
#define FFN (4*DD)            // 4096

typedef __attribute__((ext_vector_type(8))) __bf16 bf16x8;
typedef __attribute__((ext_vector_type(4))) __bf16 bf16x4;
typedef __attribute__((ext_vector_type(4))) float f32x4;

// Q pre-scale: 1/sqrt(64) * log2(e)  (softmax runs in exp2 domain)
#define QSCALE 0.18033688011112042f

__device__ __forceinline__ ushort f2b(float f) {
    union { float f; uint32_t u; } x; x.f = f;
    uint32_t r = x.u + 0x7FFF + ((x.u >> 16) & 1);
    return (ushort)(r >> 16);
}
__device__ __forceinline__ float b2f(ushort u) {
    union { uint32_t u; float f; } x; x.u = (uint32_t)u << 16;
    return x.f;
}

// ---------------- LayerNorm (torch semantics: ddof=1, eps on std) -> bf16 ----
__global__ __launch_bounds__(256)
void ln_kernel(const float* __restrict__ x, const float* __restrict__ scale,
               const float* __restrict__ shift, ushort* __restrict__ y) {
    int row = blockIdx.x;
    const float* xr = x + (size_t)row * DD;
    ushort* yr = y + (size_t)row * DD;
    int t = threadIdx.x;
    float v[4];
    float s = 0.f, ss = 0.f;
#pragma unroll
    for (int i = 0; i < 4; ++i) {
        v[i] = xr[t + 256 * i];
        s += v[i];
        ss += v[i] * v[i];
    }
#pragma unroll
    for (int off = 32; off; off >>= 1) {
        s  += __shfl_xor(s, off);
        ss += __shfl_xor(ss, off);
    }
    __shared__ float red[8];
    int w = t >> 6;
    if ((t & 63) == 0) { red[w] = s; red[w + 4] = ss; }
    __syncthreads();
    float st  = red[0] + red[1] + red[2] + red[3];
    float sst = red[4] + red[5] + red[6] + red[7];
    float mu = st * (1.f / DD);
    float var = (sst - DD * mu * mu) * (1.f / (DD - 1));
    var = fmaxf(var, 0.f);
    float inv = 1.f / (sqrtf(var) + 1e-9f);
#pragma unroll
    for (int i = 0; i < 4; ++i) {
        int c = t + 256 * i;
        yr[c] = f2b(scale[c] * (v[i] - mu) * inv + shift[c]);
    }
}

// Fused: proj = sum_z pw_z + bo;  o2 = bf16(LN(proj + input))
__global__ __launch_bounds__(256)
void ln_res4_kernel(const ushort* __restrict__ p, const float* __restrict__ pbias,
                    const float* __restrict__ xb,
                    const float* __restrict__ scale, const float* __restrict__ shift,
                    ushort* __restrict__ yb) {
    const size_t MN = (size_t)NROW * DD;
    int row = blockIdx.x;
    ushort* ybr = yb + (size_t)row * DD;
    int t = threadIdx.x;
    float v[4];
    float s = 0.f, ss = 0.f;
#pragma unroll
    for (int i = 0; i < 4; ++i) {
        int c = t + 256 * i;
        size_t idx = (size_t)row * DD + c;
        float sum = b2f(p[idx]) + b2f(p[MN + idx]) + b2f(p[2 * MN + idx])
                  + b2f(p[3 * MN + idx]) + pbias[c] + xb[idx];
        v[i] = sum;
        s += sum;
        ss += sum * sum;
    }
#pragma unroll
    for (int off = 32; off; off >>= 1) {
        s  += __shfl_xor(s, off);
        ss += __shfl_xor(ss, off);
    }
    __shared__ float red[8];
    int w = t >> 6;
    if ((t & 63) == 0) { red[w] = s; red[w + 4] = ss; }
    __syncthreads();
    float st  = red[0] + red[1] + red[2] + red[3];
    float sst = red[4] + red[5] + red[6] + red[7];
    float mu = st * (1.f / DD);
    float var = (sst - DD * mu * mu) * (1.f / (DD - 1));
    var = fmaxf(var, 0.f);
    float inv = 1.f / (sqrtf(var) + 1e-9f);
#pragma unroll
    for (int i = 0; i < 4; ++i) {
        int c = t + 256 * i;
        ybr[c] = f2b(scale[c] * (v[i] - mu) * inv + shift[c]);
    }
}

// ---------------- fp32 -> bf16 transpose-convert for weights -----------------
__global__ __launch_bounds__(256)
void transpose_bf16_kernel(const float* __restrict__ W, ushort* __restrict__ Wt,
                           int K, int N) {
    __shared__ ushort tile[32][33];
    int tx = threadIdx.x & 31;
    int ty = threadIdx.x >> 5;      // 0..7
    int n0 = blockIdx.x * 32;
    int k0 = blockIdx.y * 32;
#pragma unroll
    for (int i = 0; i < 32; i += 8)
        tile[ty + i][tx] = f2b(W[(size_t)(k0 + ty + i) * N + n0 + tx]);
    __syncthreads();
#pragma unroll
    for (int i = 0; i < 32; i += 8)
        Wt[(size_t)(n0 + ty + i) * K + k0 + tx] = tile[tx][ty + i];
}

// fused 4x 1024x1024 transpose (z selects Wq/Wk/Wv/Wo; dst slabs contiguous)
__global__ __launch_bounds__(256)
void transpose4_bf16_kernel(const float* __restrict__ W0, const float* __restrict__ W1,
                            const float* __restrict__ W2, const float* __restrict__ W3,
                            ushort* __restrict__ Wt) {
    __shared__ ushort tile[32][33];
    int z = blockIdx.z;
    const float* W = z == 0 ? W0 : (z == 1 ? W1 : (z == 2 ? W2 : W3));
    ushort* dst = Wt + (size_t)z * DD * DD;
    int tx = threadIdx.x & 31;
    int ty = threadIdx.x >> 5;      // 0..7
    int n0 = blockIdx.x * 32;
    int k0 = blockIdx.y * 32;
#pragma unroll
    for (int i = 0; i < 32; i += 8)
        tile[ty + i][tx] = f2b(W[(size_t)(k0 + ty + i) * DD + n0 + tx]);
    __syncthreads();
#pragma unroll
    for (int i = 0; i < 32; i += 8)
        dst[(size_t)(n0 + ty + i) * DD + k0 + tx] = tile[tx][ty + i];
}

// ---------------- FFN2 reduce (4-way bf16 partials + residual) ---------------
__global__ __launch_bounds__(256)
void reduce_ffn2_kernel(const ushort* __restrict__ p, const float* __restrict__ bias,
                        const ushort* __restrict__ res, float* __restrict__ out) {
    const size_t MN = (size_t)NROW * DD;
    int i = (blockIdx.x * 256 + threadIdx.x) * 4;
    ushort4 a = *reinterpret_cast<const ushort4*>(p + i);
    ushort4 b = *reinterpret_cast<const ushort4*>(p + MN + i);
    ushort4 c4 = *reinterpret_cast<const ushort4*>(p + 2 * MN + i);
    ushort4 d4 = *reinterpret_cast<const ushort4*>(p + 3 * MN + i);
    ushort4 r = *reinterpret_cast<const ushort4*>(res + i);
    int c = i & (DD - 1);
    float4 bs = *reinterpret_cast<const float4*>(bias + c);
    float4 o;
    o.x = b2f(a.x) + b2f(b.x) + b2f(c4.x) + b2f(d4.x) + bs.x + b2f(r.x);
    o.y = b2f(a.y) + b2f(b.y) + b2f(c4.y) + b2f(d4.y) + bs.y + b2f(r.y);
    o.z = b2f(a.z) + b2f(b.z) + b2f(c4.z) + b2f(d4.z) + bs.z + b2f(r.z);
    o.w = b2f(a.w) + b2f(b.w) + b2f(c4.w) + b2f(d4.w) + bs.w + b2f(r.w);
    *reinterpret_cast<float4*>(out + i) = o;
}

// ---------------- bf16 MFMA GEMM: 8 waves, DEPTH ring, BM=128 x BN tile ------
#define GBM 128
#define GBK 32

template <int MODE, bool BF16_OUT, int DEPTH, int BN>
__global__ __launch_bounds__(512)
void gemm_bf16_kernel(const ushort* __restrict__ A, const ushort* __restrict__ Wt,
                      const float* __restrict__ bias, const ushort* __restrict__ addsrc,
                      void* __restrict__ Cout, int M, int N, int K, int lda,
                      const float* __restrict__ bias2, const float* __restrict__ bias3,
                      void* __restrict__ out2, void* __restrict__ out3) {
    __shared__ ushort As[DEPTH][GBM * GBK];   // DEPTH x 8KB
    __shared__ ushort Bs[DEPTH][BN * GBK];    // DEPTH x BN/128 x 8KB
    constexpr int NF = BN / 64;               // B-frags per wave (2 or 4)

    int tid = threadIdx.x;
    int lane = tid & 63;
    int wid = tid >> 6;              // 0..7
    int wr = wid >> 2, wc = wid & 3; // 2 x 4 wave grid

    int gx = gridDim.x;
    int nwg = gx * gridDim.y;
    int orig = blockIdx.y * gx + blockIdx.x;
    int q8 = nwg >> 3;
    int swz = (orig & 7) * q8 + (orig >> 3);
    int bx = swz % gx, by = swz / gx;

    int brow = by * GBM;
    int bcol = bx * BN;
    size_t koff = (size_t)blockIdx.z * K;

    int lrow = lane & 15;
    int kgrp = lane >> 4;

    f32x4 acc[4][NF] = {};

    auto stage = [&](int buf, int k0) {
        {
            int row = tid >> 2;
            int gran = (tid & 3) ^ ((row >> 1) & 3);
            const char* ga = (const char*)A +
                ((size_t)(brow + row) * lda + koff + k0) * 2 + gran * 16;
            __builtin_amdgcn_global_load_lds(
                (const __attribute__((address_space(1))) uint32_t*)ga,
                (__attribute__((address_space(3))) uint32_t*)(&As[buf][0] + (wid * 16) * GBK),
                16, 0, 0);
        }
#pragma unroll
        for (int i = 0; i < BN / 128; ++i) {
            int idx = i * 512 + tid;
            int row = idx >> 2;
            int gran = (idx & 3) ^ ((row >> 1) & 3);
            const char* gb = (const char*)Wt +
                ((size_t)(bcol + row) * lda + koff + k0) * 2 + gran * 16;
            __builtin_amdgcn_global_load_lds(
                (const __attribute__((address_space(1))) uint32_t*)gb,
                (__attribute__((address_space(3))) uint32_t*)(&Bs[buf][0] + (i * 128 + wid * 16) * GBK),
                16, 0, 0);
        }
    };

    int nk = K / GBK;
    constexpr int PRE = DEPTH - 1;
#pragma unroll
    for (int s = 0; s < PRE; ++s)
        if (s < nk) stage(s, s * GBK);

    int cur = 0, stg = PRE;
    for (int t = 0; t < nk; ++t) {
        __builtin_amdgcn_sched_barrier(0);
        int rem = nk - 1 - t;
        if constexpr (DEPTH == 3 && BN == 128) {
            if (rem >= 1)      asm volatile("s_waitcnt vmcnt(2)" ::: "memory");
            else               asm volatile("s_waitcnt vmcnt(0)" ::: "memory");
        } else if constexpr (DEPTH == 3 && BN == 256) {
            if (rem >= 1)      asm volatile("s_waitcnt vmcnt(3)" ::: "memory");
            else               asm volatile("s_waitcnt vmcnt(0)" ::: "memory");
        } else {
            asm volatile("s_waitcnt vmcnt(0)" ::: "memory");
        }
        asm volatile("s_barrier" ::: "memory");
        if (t + PRE < nk) stage(stg, (t + PRE) * GBK);

        bf16x8 afrag[4], bfrag[NF];
#pragma unroll
        for (int mi = 0; mi < 4; ++mi) {
            int row = wr * 64 + mi * 16 + lrow;
            int gran = kgrp ^ ((row >> 1) & 3);
            afrag[mi] = *(const bf16x8*)((const char*)&As[cur][0] + row * 64 + gran * 16);
        }
#pragma unroll
        for (int ni = 0; ni < NF; ++ni) {
            int row = wc * (BN / 4) + ni * 16 + lrow;
            int gran = kgrp ^ ((row >> 1) & 3);
            bfrag[ni] = *(const bf16x8*)((const char*)&Bs[cur][0] + row * 64 + gran * 16);
        }
#pragma unroll
        for (int mi = 0; mi < 4; ++mi)
#pragma unroll
            for (int ni = 0; ni < NF; ++ni)
                acc[mi][ni] = __builtin_amdgcn_mfma_f32_16x16x32_bf16(
                    afrag[mi], bfrag[ni], acc[mi][ni], 0, 0, 0);

        cur = (cur == DEPTH - 1) ? 0 : cur + 1;
        stg = (stg == DEPTH - 1) ? 0 : stg + 1;
    }

    if (MODE == 3) {
        int which = bcol >> 10;
        const float* bs = which == 0 ? bias : (which == 1 ? bias2 : bias3);
#pragma unroll
        for (int ni = 0; ni < NF; ++ni) {
            int col = bcol + wc * (BN / 4) + ni * 16 + lrow;
            int lcol = col & 1023;
            float bsv = bs[lcol];
#pragma unroll
            for (int mi = 0; mi < 4; ++mi) {
                f32x4 a = acc[mi][ni];
#pragma unroll
                for (int j = 0; j < 4; ++j) {
                    int row = brow + wr * 64 + mi * 16 + kgrp * 4 + j;
                    float val = a[j] + bsv;
                    if (which == 2) {
                        size_t idx = (size_t)(row >> 11) * ((size_t)DD * SS)
                                   + (size_t)lcol * SS + (row & (SS - 1));
                        ((ushort*)out3)[idx] = f2b(val);
                    } else if (which == 0) {
                        ((ushort*)Cout)[(size_t)row * DD + lcol] = f2b(val * QSCALE);
                    } else {
                        ((ushort*)out2)[(size_t)row * DD + lcol] = f2b(val);
                    }
                }
            }
        }
        return;
    }

    if (MODE == 4) {
        ushort* dst = (ushort*)Cout + (size_t)blockIdx.z * ((size_t)M * N);
#pragma unroll
        for (int ni = 0; ni < NF; ++ni) {
            int col = bcol + wc * (BN / 4) + ni * 16 + lrow;
#pragma unroll
            for (int mi = 0; mi < 4; ++mi) {
                f32x4 a = acc[mi][ni];
#pragma unroll
                for (int j = 0; j < 4; ++j) {
                    int row = brow + wr * 64 + mi * 16 + kgrp * 4 + j;
                    dst[(size_t)row * N + col] = f2b(a[j]);
                }
            }
        }
        return;
    }

#pragma unroll
    for (int ni = 0; ni < NF; ++ni) {
        int col = bcol + wc * (BN / 4) + ni * 16 + lrow;
        float bsv = bias[col];
#pragma unroll
        for (int mi = 0; mi < 4; ++mi) {
            f32x4 a = acc[mi][ni];
#pragma unroll
            for (int j = 0; j < 4; ++j) {
                int row = brow + wr * 64 + mi * 16 + kgrp * 4 + j;
                float val = a[j] + bsv;
                if (MODE == 1) val = fmaxf(val, 0.f);
                if (BF16_OUT)
                    ((ushort*)Cout)[(size_t)row * N + col] = f2b(val);
                else
                    ((float*)Cout)[(size_t)row * N + col] = val;
            }
        }
    }
}

// ---------------- bf16 MFMA causal flash attention (paired q-tiles) ----------
__global__ __launch_bounds__(512)
void attn_mfma_kernel(const ushort* __restrict__ Qg, const ushort* __restrict__ Kg,
                      const ushort* __restrict__ Vtg, ushort* __restrict__ Og) {
    __shared__ ushort Qs[128 * 64];       // 16KB; reused as Ps after Q hoist
    __shared__ ushort Ks[2][64 * 64];     // 16KB
    __shared__ ushort Vs[2][64 * 64];     // 16KB

    int tid = threadIdx.x;
    int lane = tid & 63;
    int wid = tid >> 6;              // 0..7
    int bh = blockIdx.x;
    int b = bh >> 4, h = bh & 15;
    int y = blockIdx.y;              // 0..15
    int pr = (y < 8) ? y : 23 - y;
    int qp0 = pr * 128;
    int nt = (qp0 >> 6) + 2;

    const ushort* Qbase = Qg + ((size_t)(b * SS + qp0)) * DD + h * DH;
    const ushort* Kbase = Kg + ((size_t)(b * SS)) * DD + h * DH;
    const ushort* Vbase = Vtg + (size_t)bh * DH * SS;

    int g = lane >> 4;
    int lr = lane & 15;

    auto stageKV = [&](int buf, int k0) {
        int rr = wid * 8 + (lane >> 3);
        int gg = (lane & 7) ^ (rr & 7);
        const ushort* srck = Kbase + (size_t)(k0 + rr) * DD + gg * 8;
        __builtin_amdgcn_global_load_lds(
            (const __attribute__((address_space(1))) uint32_t*)srck,
            (__attribute__((address_space(3))) uint32_t*)(&Ks[buf][0] + (wid * 8) * 64),
            16, 0, 0);
        const ushort* srcv = Vbase + (size_t)rr * SS + k0 + gg * 8;
        __builtin_amdgcn_global_load_lds(
            (const __attribute__((address_space(1))) uint32_t*)srcv,
            (__attribute__((address_space(3))) uint32_t*)(&Vs[buf][0] + (wid * 8) * 64),
            16, 0, 0);
    };

    {
        int rr0 = wid * 16 + (lane >> 3);
        int g0 = lane & 7;
#pragma unroll
        for (int i = 0; i < 2; ++i) {
            int rr = rr0 + i * 8;
            int gg = g0 ^ (rr & 7);
            const ushort* src = Qbase + (size_t)rr * DD + gg * 8;
            __builtin_amdgcn_global_load_lds(
                (const __attribute__((address_space(1))) uint32_t*)src,
                (__attribute__((address_space(3))) uint32_t*)(Qs + (wid * 16 + i * 8) * 64),
                16, 0, 0);
        }
    }
    stageKV(0, 0);
    asm volatile("s_waitcnt vmcnt(2)" ::: "memory");

    int offF[8];
#pragma unroll
    for (int ni = 0; ni < 4; ++ni)
#pragma unroll
        for (int ks = 0; ks < 2; ++ks) {
            int r = ni * 16 + lr;
            offF[ni * 2 + ks] = r * 128 + (((ks * 4 + g) ^ (r & 7)) << 4);
        }
    int rq = wid * 16 + lr;
    int offQ[2];
#pragma unroll
    for (int ks = 0; ks < 2; ++ks)
        offQ[ks] = rq * 128 + (((ks * 4 + g) ^ (rq & 7)) << 4);
    int offPw[4];
#pragma unroll
    for (int ni = 0; ni < 4; ++ni)
        offPw[ni] = rq * 128 + (((ni * 2 + (g >> 1)) ^ (rq & 7)) << 4) + (g & 1) * 8;

    bf16x8 aq[2];
#pragma unroll
    for (int ks = 0; ks < 2; ++ks)
        aq[ks] = *(const bf16x8*)((const char*)Qs + offQ[ks]);
    ushort* Ps = Qs;

    f32x4 oacc[4] = {};
    float m = -INFINITY, l = 0.f;
    const float THR = 11.0f;
    int qa = qp0 + wid * 16 + lr;
    int qw0 = qp0 + wid * 16;

    int cur = 0;
    for (int t = 0; t < nt; ++t) {
        __builtin_amdgcn_sched_barrier(0);
        asm volatile("s_waitcnt vmcnt(0)" ::: "memory");
        asm volatile("s_barrier" ::: "memory");
        if (t + 1 < nt) stageKV(cur ^ 1, (t + 1) * 64);
        int k0 = t * 64;

        f32x4 sacc[4] = {};
        __builtin_amdgcn_s_setprio(1);
#pragma unroll
        for (int ni = 0; ni < 4; ++ni)
#pragma unroll
            for (int ks = 0; ks < 2; ++ks) {
                bf16x8 bk = *(const bf16x8*)((const char*)&Ks[cur][0] + offF[ni * 2 + ks]);
                sacc[ni] = __builtin_amdgcn_mfma_f32_16x16x32_bf16(bk, aq[ks], sacc[ni], 0, 0, 0);
            }
        __builtin_amdgcn_s_setprio(0);

        if (k0 + 63 > qw0) {
#pragma unroll
            for (int ni = 0; ni < 4; ++ni) {
#pragma unroll
                for (int j = 0; j < 4; ++j) {
                    int key = k0 + ni * 16 + g * 4 + j;
                    if (key > qa) sacc[ni][j] = -INFINITY;
                }
            }
        }

        float mx = sacc[0][0];
#pragma unroll
        for (int ni = 0; ni < 4; ++ni)
#pragma unroll
            for (int j = 0; j < 4; ++j) mx = fmaxf(mx, sacc[ni][j]);
        mx = fmaxf(mx, __shfl_xor(mx, 16));
        mx = fmaxf(mx, __shfl_xor(mx, 32));

        if (__any(mx > m + THR)) {
            float mn = fmaxf(m, mx);
            float corr = __builtin_amdgcn_exp2f(m - mn);
            m = mn;
            l *= corr;
            float cj[4];
#pragma unroll
            for (int j = 0; j < 4; ++j)
                cj[j] = __shfl(corr, (lane & 48) | (g * 4 + j));
#pragma unroll
            for (int ni = 0; ni < 4; ++ni)
#pragma unroll
                for (int j = 0; j < 4; ++j) oacc[ni][j] *= cj[j];
        }

        float p[4][4];
        float rs = 0.f;
#pragma unroll
        for (int ni = 0; ni < 4; ++ni)
#pragma unroll
            for (int j = 0; j < 4; ++j) {
                p[ni][j] = __builtin_amdgcn_exp2f(sacc[ni][j] - m);
                rs += p[ni][j];
            }
        rs += __shfl_xor(rs, 16);
        rs += __shfl_xor(rs, 32);
        l += rs;

#pragma unroll
        for (int ni = 0; ni < 4; ++ni) {
            bf16x4 w4 = { (__bf16)p[ni][0], (__bf16)p[ni][1],
                          (__bf16)p[ni][2], (__bf16)p[ni][3] };
            *(bf16x4*)((char*)Ps + offPw[ni]) = w4;
        }
        asm volatile("s_waitcnt lgkmcnt(0)" ::: "memory");

        bf16x8 ap[2];
#pragma unroll
        for (int ks = 0; ks < 2; ++ks)
            ap[ks] = *(const bf16x8*)((const char*)Ps + offQ[ks]);
        __builtin_amdgcn_s_setprio(1);
#pragma unroll
        for (int ni = 0; ni < 4; ++ni)
#pragma unroll
            for (int ks = 0; ks < 2; ++ks) {
                bf16x8 bv = *(const bf16x8*)((const char*)&Vs[cur][0] + offF[ni * 2 + ks]);
                oacc[ni] = __builtin_amdgcn_mfma_f32_16x16x32_bf16(ap[ks], bv, oacc[ni], 0, 0, 0);
            }
        __builtin_amdgcn_s_setprio(0);
        cur ^= 1;
    }

#pragma unroll
    for (int j = 0; j < 4; ++j) {
        float lj = __shfl(l, (lane & 48) | (g * 4 + j));
        float inv = 1.f / lj;
        int gr = qp0 + wid * 16 + g * 4 + j;
#pragma unroll
        for (int ni = 0; ni < 4; ++ni) {
            int d = ni * 16 + lr;
            Og[((size_t)(b * SS + gr)) * DD + h * DH + d] = f2b(oacc[ni][j] * inv);
        }
    }
}

// ---------------- Launch ------------------------------------------------------
extern "C" void kernel_launch(void* const* d_in, const int* in_sizes, int n_in,
                              void* d_out, int out_size, void* d_ws, size_t ws_size,
                              hipStream_t stream) {
    const float* inputs    = (const float*)d_in[0];
    const float* ln1_scale = (const float*)d_in[1];
    const float* ln1_shift = (const float*)d_in[2];
    const float* Wq = (const float*)d_in[3];
    const float* bq = (const float*)d_in[4];
    const float* Wk = (const float*)d_in[5];
    const float* bk = (const float*)d_in[6];
    const float* Wv = (const float*)d_in[7];
    const float* bv = (const float*)d_in[8];
    const float* Wo = (const float*)d_in[9];
    const float* bo = (const float*)d_in[10];
    const float* W1 = (const float*)d_in[11];
    const float* b1 = (const float*)d_in[12];
    const float* W2 = (const float*)d_in[13];
    const float* b2 = (const float*)d_in[14];
    const float* ln2_scale = (const float*)d_in[15];
    const float* ln2_shift = (const float*)d_in[16];
    float* out = (float*)d_out;

    const size_t MB = 1024 * 1024;
    char* w = (char*)d_ws;
    ushort* q_b   = (ushort*)(w + 0 * MB);     // 8MB (dead after attn)
    ushort* k_b   = (ushort*)(w + 8 * MB);     // 8MB (dead after attn)
    ushort* vt_b  = (ushort*)(w + 16 * MB);    // 8MB (dead after attn)
    ushort* att_b = (ushort*)(w + 24 * MB);    // 8MB (dead after Wo GEMM)
    ushort* pw    = (ushort*)(w + 32 * MB);    // 32MB Wo split-4 bf16 partials
    ushort* o2_b  = (ushort*)(w + 8 * MB);     // 8MB (over k_b)
    ushort* pf    = (ushort*)(w + 16 * MB);    // 32MB FFN2 split-4 bf16 partials
    ushort* h1_b  = (ushort*)(w + 64 * MB);    // 32MB
    ushort* wq_t  = (ushort*)(w + 96 * MB);    // 2MB (q/k/v/o contiguous slabs)
    ushort* wk_t  = (ushort*)(w + 98 * MB);
    ushort* wv_t  = (ushort*)(w + 100 * MB);
    ushort* wo_t  = (ushort*)(w + 102 * MB);
    ushort* w1_t  = (ushort*)(w + 104 * MB);   // 8MB
    ushort* w2_t  = (ushort*)(w + 112 * MB);   // 8MB
    ushort* xn_b  = (ushort*)(w + 120 * MB);   // 8MB

    // 0. weight convert+transpose
    transpose4_bf16_kernel<<<dim3(DD / 32, DD / 32, 4), 256, 0, stream>>>(
        Wq, Wk, Wv, Wo, wq_t);
    transpose_bf16_kernel<<<dim3(FFN / 32, DD / 32), 256, 0, stream>>>(W1, w1_t, DD, FFN);
    transpose_bf16_kernel<<<dim3(DD / 32, FFN / 32), 256, 0, stream>>>(W2, w2_t, FFN, DD);

    // 1. LN1 -> bf16
    ln_kernel<<<NROW, 256, 0, stream>>>(inputs, ln1_scale, ln1_shift, xn_b);

    // 2. Fused QKV projection (N=3072; V transposed per head; q pre-scaled).
    dim3 gqkv(3 * DD / 128, NROW / GBM, 1);   // 24 x 32
    gemm_bf16_kernel<3, true, 3, 128><<<gqkv, 512, 0, stream>>>(
        xn_b, wq_t, bq, nullptr, q_b, NROW, 3 * DD, DD, DD, bk, bv, k_b, vt_b);

    // 3. MFMA flash attention -> att_b (bf16). 512 blocks x 8 waves, 48KB.
    dim3 ga(BB * HH, SS / 128);
    attn_mfma_kernel<<<ga, 512, 0, stream>>>(q_b, k_b, vt_b, att_b);

    // 4. Output projection, split-K=4, BN=256 -> bf16 partials pw.
    dim3 gwo(DD / 256, NROW / GBM, 4);        // 4 x 32 x 4
    gemm_bf16_kernel<4, false, 3, 256><<<gwo, 512, 0, stream>>>(
        att_b, wo_t, nullptr, nullptr, pw, NROW, DD, DD / 4, DD, nullptr, nullptr, nullptr, nullptr);

    // 5. fused reduce(pw)+bias -> +input -> LN2 -> o2 (bf16)
    ln_res4_kernel<<<NROW, 256, 0, stream>>>(pw, bo, inputs, ln2_scale, ln2_shift, o2_b);

    // 6. FFN up + relu -> h1 (bf16). BN=256: 512 blocks at 72KB = 2/CU round.
    dim3 g2(FFN / 256, NROW / GBM, 1);        // 16 x 32
    gemm_bf16_kernel<1, true, 3, 256><<<g2, 512, 0, stream>>>(
        o2_b, w1_t, b1, nullptr, h1_b, NROW, FFN, DD, DD, nullptr, nullptr, nullptr, nullptr);

    // 7. FFN down, split-K=4, BN=256 -> bf16 partials pf. 512 blocks = round.
    dim3 gf2(DD / 256, NROW / GBM, 4);        // 4 x 32 x 4
    gemm_bf16_kernel<4, false, 3, 256><<<gf2, 512, 0, stream>>>(
        h1_b, w2_t, nullptr, nullptr, pf, NROW, DD, FFN / 4, FFN, nullptr, nullptr, nullptr, nullptr);
    reduce_ffn2_kernel<<<(NROW * DD / 4) / 256, 256, 0, stream>>>(pf, b2, o2_b, out);
}

// Round 22
// 227.983 us; speedup vs baseline: 1.0145x; 1.0021x over previous
//
#include <hip/hip_runtime.h>
#include <hip/hip_bf16.h>
#include <math.h>

// Problem constants
#define BB 2
#define SS 2048
#define DD 1024
#define HH 16
#define DH 64
#define NROW (BB*SS)          // 4096
#define FFN (4*DD)            // 4096

typedef __attribute__((ext_vector_type(8))) __bf16 bf16x8;
typedef __attribute__((ext_vector_type(4))) __bf16 bf16x4;
typedef __attribute__((ext_vector_type(4))) float f32x4;

// Q pre-scale: 1/sqrt(64) * log2(e)  (softmax runs in exp2 domain)
#define QSCALE 0.18033688011112042f

__device__ __forceinline__ ushort f2b(float f) {
    union { float f; uint32_t u; } x; x.f = f;
    uint32_t r = x.u + 0x7FFF + ((x.u >> 16) & 1);
    return (ushort)(r >> 16);
}
__device__ __forceinline__ float b2f(ushort u) {
    union { uint32_t u; float f; } x; x.u = (uint32_t)u << 16;
    return x.f;
}

// ---------------- LayerNorm (torch semantics: ddof=1, eps on std) -> bf16 ----
__global__ __launch_bounds__(256)
void ln_kernel(const float* __restrict__ x, const float* __restrict__ scale,
               const float* __restrict__ shift, ushort* __restrict__ y) {
    int row = blockIdx.x;
    const float* xr = x + (size_t)row * DD;
    ushort* yr = y + (size_t)row * DD;
    int t = threadIdx.x;
    float v[4];
    float s = 0.f, ss = 0.f;
#pragma unroll
    for (int i = 0; i < 4; ++i) {
        v[i] = xr[t + 256 * i];
        s += v[i];
        ss += v[i] * v[i];
    }
#pragma unroll
    for (int off = 32; off; off >>= 1) {
        s  += __shfl_xor(s, off);
        ss += __shfl_xor(ss, off);
    }
    __shared__ float red[8];
    int w = t >> 6;
    if ((t & 63) == 0) { red[w] = s; red[w + 4] = ss; }
    __syncthreads();
    float st  = red[0] + red[1] + red[2] + red[3];
    float sst = red[4] + red[5] + red[6] + red[7];
    float mu = st * (1.f / DD);
    float var = (sst - DD * mu * mu) * (1.f / (DD - 1));
    var = fmaxf(var, 0.f);
    float inv = 1.f / (sqrtf(var) + 1e-9f);
#pragma unroll
    for (int i = 0; i < 4; ++i) {
        int c = t + 256 * i;
        yr[c] = f2b(scale[c] * (v[i] - mu) * inv + shift[c]);
    }
}

// Fused: proj = sum_z pw_z + bo;  o2 = bf16(LN(proj + input))
__global__ __launch_bounds__(256)
void ln_res4_kernel(const ushort* __restrict__ p, const float* __restrict__ pbias,
                    const float* __restrict__ xb,
                    const float* __restrict__ scale, const float* __restrict__ shift,
                    ushort* __restrict__ yb) {
    const size_t MN = (size_t)NROW * DD;
    int row = blockIdx.x;
    ushort* ybr = yb + (size_t)row * DD;
    int t = threadIdx.x;
    float v[4];
    float s = 0.f, ss = 0.f;
#pragma unroll
    for (int i = 0; i < 4; ++i) {
        int c = t + 256 * i;
        size_t idx = (size_t)row * DD + c;
        float sum = b2f(p[idx]) + b2f(p[MN + idx]) + b2f(p[2 * MN + idx])
                  + b2f(p[3 * MN + idx]) + pbias[c] + xb[idx];
        v[i] = sum;
        s += sum;
        ss += sum * sum;
    }
#pragma unroll
    for (int off = 32; off; off >>= 1) {
        s  += __shfl_xor(s, off);
        ss += __shfl_xor(ss, off);
    }
    __shared__ float red[8];
    int w = t >> 6;
    if ((t & 63) == 0) { red[w] = s; red[w + 4] = ss; }
    __syncthreads();
    float st  = red[0] + red[1] + red[2] + red[3];
    float sst = red[4] + red[5] + red[6] + red[7];
    float mu = st * (1.f / DD);
    float var = (sst - DD * mu * mu) * (1.f / (DD - 1));
    var = fmaxf(var, 0.f);
    float inv = 1.f / (sqrtf(var) + 1e-9f);
#pragma unroll
    for (int i = 0; i < 4; ++i) {
        int c = t + 256 * i;
        ybr[c] = f2b(scale[c] * (v[i] - mu) * inv + shift[c]);
    }
}

// fused 4x 1024x1024 transpose (z selects Wq/Wk/Wv/Wo; dst slabs contiguous)
__global__ __launch_bounds__(256)
void transpose4_bf16_kernel(const float* __restrict__ W0, const float* __restrict__ W1,
                            const float* __restrict__ W2, const float* __restrict__ W3,
                            ushort* __restrict__ Wt) {
    __shared__ ushort tile[32][33];
    int z = blockIdx.z;
    const float* W = z == 0 ? W0 : (z == 1 ? W1 : (z == 2 ? W2 : W3));
    ushort* dst = Wt + (size_t)z * DD * DD;
    int tx = threadIdx.x & 31;
    int ty = threadIdx.x >> 5;      // 0..7
    int n0 = blockIdx.x * 32;
    int k0 = blockIdx.y * 32;
#pragma unroll
    for (int i = 0; i < 32; i += 8)
        tile[ty + i][tx] = f2b(W[(size_t)(k0 + ty + i) * DD + n0 + tx]);
    __syncthreads();
#pragma unroll
    for (int i = 0; i < 32; i += 8)
        dst[(size_t)(n0 + ty + i) * DD + k0 + tx] = tile[tx][ty + i];
}

// fused W1 (1024x4096) + W2 (4096x1024) transpose in one launch (z=0: W1, z=1: W2)
__global__ __launch_bounds__(256)
void transpose_ffn_kernel(const float* __restrict__ W1, const float* __restrict__ W2,
                          ushort* __restrict__ W1t, ushort* __restrict__ W2t) {
    __shared__ ushort tile[32][33];
    int z = blockIdx.z;
    const float* W = z == 0 ? W1 : W2;
    ushort* Wt = z == 0 ? W1t : W2t;
    int K = z == 0 ? DD : FFN;
    int N = z == 0 ? FFN : DD;
    int n0 = (z == 0 ? blockIdx.x : blockIdx.y) * 32;
    int k0 = (z == 0 ? blockIdx.y : blockIdx.x) * 32;
    int tx = threadIdx.x & 31;
    int ty = threadIdx.x >> 5;      // 0..7
#pragma unroll
    for (int i = 0; i < 32; i += 8)
        tile[ty + i][tx] = f2b(W[(size_t)(k0 + ty + i) * N + n0 + tx]);
    __syncthreads();
#pragma unroll
    for (int i = 0; i < 32; i += 8)
        Wt[(size_t)(n0 + ty + i) * K + k0 + tx] = tile[tx][ty + i];
}

// ---------------- FFN2 reduce (4-way bf16 partials + residual) ---------------
__global__ __launch_bounds__(256)
void reduce_ffn2_kernel(const ushort* __restrict__ p, const float* __restrict__ bias,
                        const ushort* __restrict__ res, float* __restrict__ out) {
    const size_t MN = (size_t)NROW * DD;
    int i = (blockIdx.x * 256 + threadIdx.x) * 4;
    ushort4 a = *reinterpret_cast<const ushort4*>(p + i);
    ushort4 b = *reinterpret_cast<const ushort4*>(p + MN + i);
    ushort4 c4 = *reinterpret_cast<const ushort4*>(p + 2 * MN + i);
    ushort4 d4 = *reinterpret_cast<const ushort4*>(p + 3 * MN + i);
    ushort4 r = *reinterpret_cast<const ushort4*>(res + i);
    int c = i & (DD - 1);
    float4 bs = *reinterpret_cast<const float4*>(bias + c);
    float4 o;
    o.x = b2f(a.x) + b2f(b.x) + b2f(c4.x) + b2f(d4.x) + bs.x + b2f(r.x);
    o.y = b2f(a.y) + b2f(b.y) + b2f(c4.y) + b2f(d4.y) + bs.y + b2f(r.y);
    o.z = b2f(a.z) + b2f(b.z) + b2f(c4.z) + b2f(d4.z) + bs.z + b2f(r.z);
    o.w = b2f(a.w) + b2f(b.w) + b2f(c4.w) + b2f(d4.w) + bs.w + b2f(r.w);
    *reinterpret_cast<float4*>(out + i) = o;
}

// ---------------- bf16 MFMA GEMM: 8 waves, DEPTH ring, BM=128 x BN tile ------
#define GBM 128
#define GBK 32

template <int MODE, bool BF16_OUT, int DEPTH, int BN>
__global__ __launch_bounds__(512)
void gemm_bf16_kernel(const ushort* __restrict__ A, const ushort* __restrict__ Wt,
                      const float* __restrict__ bias, const ushort* __restrict__ addsrc,
                      void* __restrict__ Cout, int M, int N, int K, int lda,
                      const float* __restrict__ bias2, const float* __restrict__ bias3,
                      void* __restrict__ out2, void* __restrict__ out3) {
    __shared__ ushort As[DEPTH][GBM * GBK];   // DEPTH x 8KB
    __shared__ ushort Bs[DEPTH][BN * GBK];    // DEPTH x BN/128 x 8KB
    constexpr int NF = BN / 64;               // B-frags per wave (2 or 4)

    int tid = threadIdx.x;
    int lane = tid & 63;
    int wid = tid >> 6;              // 0..7
    int wr = wid >> 2, wc = wid & 3; // 2 x 4 wave grid

    int gx = gridDim.x;
    int nwg = gx * gridDim.y;
    int orig = blockIdx.y * gx + blockIdx.x;
    int q8 = nwg >> 3;
    int swz = (orig & 7) * q8 + (orig >> 3);
    int bx = swz % gx, by = swz / gx;

    int brow = by * GBM;
    int bcol = bx * BN;
    size_t koff = (size_t)blockIdx.z * K;

    int lrow = lane & 15;
    int kgrp = lane >> 4;

    f32x4 acc[4][NF] = {};

    auto stage = [&](int buf, int k0) {
        {
            int row = tid >> 2;
            int gran = (tid & 3) ^ ((row >> 1) & 3);
            const char* ga = (const char*)A +
                ((size_t)(brow + row) * lda + koff + k0) * 2 + gran * 16;
            __builtin_amdgcn_global_load_lds(
                (const __attribute__((address_space(1))) uint32_t*)ga,
                (__attribute__((address_space(3))) uint32_t*)(&As[buf][0] + (wid * 16) * GBK),
                16, 0, 0);
        }
#pragma unroll
        for (int i = 0; i < BN / 128; ++i) {
            int idx = i * 512 + tid;
            int row = idx >> 2;
            int gran = (idx & 3) ^ ((row >> 1) & 3);
            const char* gb = (const char*)Wt +
                ((size_t)(bcol + row) * lda + koff + k0) * 2 + gran * 16;
            __builtin_amdgcn_global_load_lds(
                (const __attribute__((address_space(1))) uint32_t*)gb,
                (__attribute__((address_space(3))) uint32_t*)(&Bs[buf][0] + (i * 128 + wid * 16) * GBK),
                16, 0, 0);
        }
    };

    int nk = K / GBK;
    constexpr int PRE = DEPTH - 1;
#pragma unroll
    for (int s = 0; s < PRE; ++s)
        if (s < nk) stage(s, s * GBK);

    int cur = 0, stg = PRE;
    for (int t = 0; t < nk; ++t) {
        __builtin_amdgcn_sched_barrier(0);
        int rem = nk - 1 - t;
        if constexpr (DEPTH == 3 && BN == 128) {
            if (rem >= 1)      asm volatile("s_waitcnt vmcnt(2)" ::: "memory");
            else               asm volatile("s_waitcnt vmcnt(0)" ::: "memory");
        } else if constexpr (DEPTH == 3 && BN == 256) {
            if (rem >= 1)      asm volatile("s_waitcnt vmcnt(3)" ::: "memory");
            else               asm volatile("s_waitcnt vmcnt(0)" ::: "memory");
        } else {
            asm volatile("s_waitcnt vmcnt(0)" ::: "memory");
        }
        asm volatile("s_barrier" ::: "memory");
        if (t + PRE < nk) stage(stg, (t + PRE) * GBK);

        bf16x8 afrag[4], bfrag[NF];
#pragma unroll
        for (int mi = 0; mi < 4; ++mi) {
            int row = wr * 64 + mi * 16 + lrow;
            int gran = kgrp ^ ((row >> 1) & 3);
            afrag[mi] = *(const bf16x8*)((const char*)&As[cur][0] + row * 64 + gran * 16);
        }
#pragma unroll
        for (int ni = 0; ni < NF; ++ni) {
            int row = wc * (BN / 4) + ni * 16 + lrow;
            int gran = kgrp ^ ((row >> 1) & 3);
            bfrag[ni] = *(const bf16x8*)((const char*)&Bs[cur][0] + row * 64 + gran * 16);
        }
#pragma unroll
        for (int mi = 0; mi < 4; ++mi)
#pragma unroll
            for (int ni = 0; ni < NF; ++ni)
                acc[mi][ni] = __builtin_amdgcn_mfma_f32_16x16x32_bf16(
                    afrag[mi], bfrag[ni], acc[mi][ni], 0, 0, 0);

        cur = (cur == DEPTH - 1) ? 0 : cur + 1;
        stg = (stg == DEPTH - 1) ? 0 : stg + 1;
    }

    if (MODE == 3) {
        int which = bcol >> 10;
        const float* bs = which == 0 ? bias : (which == 1 ? bias2 : bias3);
#pragma unroll
        for (int ni = 0; ni < NF; ++ni) {
            int col = bcol + wc * (BN / 4) + ni * 16 + lrow;
            int lcol = col & 1023;
            float bsv = bs[lcol];
#pragma unroll
            for (int mi = 0; mi < 4; ++mi) {
                f32x4 a = acc[mi][ni];
#pragma unroll
                for (int j = 0; j < 4; ++j) {
                    int row = brow + wr * 64 + mi * 16 + kgrp * 4 + j;
                    float val = a[j] + bsv;
                    if (which == 2) {
                        size_t idx = (size_t)(row >> 11) * ((size_t)DD * SS)
                                   + (size_t)lcol * SS + (row & (SS - 1));
                        ((ushort*)out3)[idx] = f2b(val);
                    } else if (which == 0) {
                        ((ushort*)Cout)[(size_t)row * DD + lcol] = f2b(val * QSCALE);
                    } else {
                        ((ushort*)out2)[(size_t)row * DD + lcol] = f2b(val);
                    }
                }
            }
        }
        return;
    }

    if (MODE == 4) {
        ushort* dst = (ushort*)Cout + (size_t)blockIdx.z * ((size_t)M * N);
#pragma unroll
        for (int ni = 0; ni < NF; ++ni) {
            int col = bcol + wc * (BN / 4) + ni * 16 + lrow;
#pragma unroll
            for (int mi = 0; mi < 4; ++mi) {
                f32x4 a = acc[mi][ni];
#pragma unroll
                for (int j = 0; j < 4; ++j) {
                    int row = brow + wr * 64 + mi * 16 + kgrp * 4 + j;
                    dst[(size_t)row * N + col] = f2b(a[j]);
                }
            }
        }
        return;
    }

#pragma unroll
    for (int ni = 0; ni < NF; ++ni) {
        int col = bcol + wc * (BN / 4) + ni * 16 + lrow;
        float bsv = bias[col];
#pragma unroll
        for (int mi = 0; mi < 4; ++mi) {
            f32x4 a = acc[mi][ni];
#pragma unroll
            for (int j = 0; j < 4; ++j) {
                int row = brow + wr * 64 + mi * 16 + kgrp * 4 + j;
                float val = a[j] + bsv;
                if (MODE == 1) val = fmaxf(val, 0.f);
                if (BF16_OUT)
                    ((ushort*)Cout)[(size_t)row * N + col] = f2b(val);
                else
                    ((float*)Cout)[(size_t)row * N + col] = val;
            }
        }
    }
}

// ---------------- bf16 MFMA causal flash attention (paired q-tiles) ----------
__global__ __launch_bounds__(512)
void attn_mfma_kernel(const ushort* __restrict__ Qg, const ushort* __restrict__ Kg,
                      const ushort* __restrict__ Vtg, ushort* __restrict__ Og) {
    __shared__ ushort Qs[128 * 64];       // 16KB; reused as Ps after Q hoist
    __shared__ ushort Ks[2][64 * 64];     // 16KB
    __shared__ ushort Vs[2][64 * 64];     // 16KB

    int tid = threadIdx.x;
    int lane = tid & 63;
    int wid = tid >> 6;              // 0..7
    int bh = blockIdx.x;
    int b = bh >> 4, h = bh & 15;
    int y = blockIdx.y;              // 0..15
    int pr = (y < 8) ? y : 23 - y;
    int qp0 = pr * 128;
    int nt = (qp0 >> 6) + 2;

    const ushort* Qbase = Qg + ((size_t)(b * SS + qp0)) * DD + h * DH;
    const ushort* Kbase = Kg + ((size_t)(b * SS)) * DD + h * DH;
    const ushort* Vbase = Vtg + (size_t)bh * DH * SS;

    int g = lane >> 4;
    int lr = lane & 15;

    auto stageKV = [&](int buf, int k0) {
        int rr = wid * 8 + (lane >> 3);
        int gg = (lane & 7) ^ (rr & 7);
        const ushort* srck = Kbase + (size_t)(k0 + rr) * DD + gg * 8;
        __builtin_amdgcn_global_load_lds(
            (const __attribute__((address_space(1))) uint32_t*)srck,
            (__attribute__((address_space(3))) uint32_t*)(&Ks[buf][0] + (wid * 8) * 64),
            16, 0, 0);
        const ushort* srcv = Vbase + (size_t)rr * SS + k0 + gg * 8;
        __builtin_amdgcn_global_load_lds(
            (const __attribute__((address_space(1))) uint32_t*)srcv,
            (__attribute__((address_space(3))) uint32_t*)(&Vs[buf][0] + (wid * 8) * 64),
            16, 0, 0);
    };

    {
        int rr0 = wid * 16 + (lane >> 3);
        int g0 = lane & 7;
#pragma unroll
        for (int i = 0; i < 2; ++i) {
            int rr = rr0 + i * 8;
            int gg = g0 ^ (rr & 7);
            const ushort* src = Qbase + (size_t)rr * DD + gg * 8;
            __builtin_amdgcn_global_load_lds(
                (const __attribute__((address_space(1))) uint32_t*)src,
                (__attribute__((address_space(3))) uint32_t*)(Qs + (wid * 16 + i * 8) * 64),
                16, 0, 0);
        }
    }
    stageKV(0, 0);
    asm volatile("s_waitcnt vmcnt(2)" ::: "memory");

    int offF[8];
#pragma unroll
    for (int ni = 0; ni < 4; ++ni)
#pragma unroll
        for (int ks = 0; ks < 2; ++ks) {
            int r = ni * 16 + lr;
            offF[ni * 2 + ks] = r * 128 + (((ks * 4 + g) ^ (r & 7)) << 4);
        }
    int rq = wid * 16 + lr;
    int offQ[2];
#pragma unroll
    for (int ks = 0; ks < 2; ++ks)
        offQ[ks] = rq * 128 + (((ks * 4 + g) ^ (rq & 7)) << 4);
    int offPw[4];
#pragma unroll
    for (int ni = 0; ni < 4; ++ni)
        offPw[ni] = rq * 128 + (((ni * 2 + (g >> 1)) ^ (rq & 7)) << 4) + (g & 1) * 8;

    bf16x8 aq[2];
#pragma unroll
    for (int ks = 0; ks < 2; ++ks)
        aq[ks] = *(const bf16x8*)((const char*)Qs + offQ[ks]);
    ushort* Ps = Qs;

    f32x4 oacc[4] = {};
    float m = -INFINITY, l = 0.f;
    const float THR = 11.0f;
    int qa = qp0 + wid * 16 + lr;
    int qw0 = qp0 + wid * 16;

    int cur = 0;
    for (int t = 0; t < nt; ++t) {
        __builtin_amdgcn_sched_barrier(0);
        asm volatile("s_waitcnt vmcnt(0)" ::: "memory");
        asm volatile("s_barrier" ::: "memory");
        if (t + 1 < nt) stageKV(cur ^ 1, (t + 1) * 64);
        int k0 = t * 64;

        f32x4 sacc[4] = {};
        __builtin_amdgcn_s_setprio(1);
#pragma unroll
        for (int ni = 0; ni < 4; ++ni)
#pragma unroll
            for (int ks = 0; ks < 2; ++ks) {
                bf16x8 bk = *(const bf16x8*)((const char*)&Ks[cur][0] + offF[ni * 2 + ks]);
                sacc[ni] = __builtin_amdgcn_mfma_f32_16x16x32_bf16(bk, aq[ks], sacc[ni], 0, 0, 0);
            }
        __builtin_amdgcn_s_setprio(0);

        if (k0 + 63 > qw0) {
#pragma unroll
            for (int ni = 0; ni < 4; ++ni) {
#pragma unroll
                for (int j = 0; j < 4; ++j) {
                    int key = k0 + ni * 16 + g * 4 + j;
                    if (key > qa) sacc[ni][j] = -INFINITY;
                }
            }
        }

        float mx = sacc[0][0];
#pragma unroll
        for (int ni = 0; ni < 4; ++ni)
#pragma unroll
            for (int j = 0; j < 4; ++j) mx = fmaxf(mx, sacc[ni][j]);
        mx = fmaxf(mx, __shfl_xor(mx, 16));
        mx = fmaxf(mx, __shfl_xor(mx, 32));

        if (__any(mx > m + THR)) {
            float mn = fmaxf(m, mx);
            float corr = __builtin_amdgcn_exp2f(m - mn);
            m = mn;
            l *= corr;
            float cj[4];
#pragma unroll
            for (int j = 0; j < 4; ++j)
                cj[j] = __shfl(corr, (lane & 48) | (g * 4 + j));
#pragma unroll
            for (int ni = 0; ni < 4; ++ni)
#pragma unroll
                for (int j = 0; j < 4; ++j) oacc[ni][j] *= cj[j];
        }

        float p[4][4];
        float rs = 0.f;
#pragma unroll
        for (int ni = 0; ni < 4; ++ni)
#pragma unroll
            for (int j = 0; j < 4; ++j) {
                p[ni][j] = __builtin_amdgcn_exp2f(sacc[ni][j] - m);
                rs += p[ni][j];
            }
        rs += __shfl_xor(rs, 16);
        rs += __shfl_xor(rs, 32);
        l += rs;

#pragma unroll
        for (int ni = 0; ni < 4; ++ni) {
            bf16x4 w4 = { (__bf16)p[ni][0], (__bf16)p[ni][1],
                          (__bf16)p[ni][2], (__bf16)p[ni][3] };
            *(bf16x4*)((char*)Ps + offPw[ni]) = w4;
        }
        asm volatile("s_waitcnt lgkmcnt(0)" ::: "memory");

        bf16x8 ap[2];
#pragma unroll
        for (int ks = 0; ks < 2; ++ks)
            ap[ks] = *(const bf16x8*)((const char*)Ps + offQ[ks]);
        __builtin_amdgcn_s_setprio(1);
#pragma unroll
        for (int ni = 0; ni < 4; ++ni)
#pragma unroll
            for (int ks = 0; ks < 2; ++ks) {
                bf16x8 bv = *(const bf16x8*)((const char*)&Vs[cur][0] + offF[ni * 2 + ks]);
                oacc[ni] = __builtin_amdgcn_mfma_f32_16x16x32_bf16(ap[ks], bv, oacc[ni], 0, 0, 0);
            }
        __builtin_amdgcn_s_setprio(0);
        cur ^= 1;
    }

#pragma unroll
    for (int j = 0; j < 4; ++j) {
        float lj = __shfl(l, (lane & 48) | (g * 4 + j));
        float inv = 1.f / lj;
        int gr = qp0 + wid * 16 + g * 4 + j;
#pragma unroll
        for (int ni = 0; ni < 4; ++ni) {
            int d = ni * 16 + lr;
            Og[((size_t)(b * SS + gr)) * DD + h * DH + d] = f2b(oacc[ni][j] * inv);
        }
    }
}

// ---------------- Launch ------------------------------------------------------
extern "C" void kernel_launch(void* const* d_in, const int* in_sizes, int n_in,
                              void* d_out, int out_size, void* d_ws, size_t ws_size,
                              hipStream_t stream) {
    const float* inputs    = (const float*)d_in[0];
    const float* ln1_scale = (const float*)d_in[1];
    const float* ln1_shift = (const float*)d_in[2];
    const float* Wq = (const float*)d_in[3];
    const float* bq = (const float*)d_in[4];
    const float* Wk = (const float*)d_in[5];
    const float* bk = (const float*)d_in[6];
    const float* Wv = (const float*)d_in[7];
    const float* bv = (const float*)d_in[8];
    const float* Wo = (const float*)d_in[9];
    const float* bo = (const float*)d_in[10];
    const float* W1 = (const float*)d_in[11];
    const float* b1 = (const float*)d_in[12];
    const float* W2 = (const float*)d_in[13];
    const float* b2 = (const float*)d_in[14];
    const float* ln2_scale = (const float*)d_in[15];
    const float* ln2_shift = (const float*)d_in[16];
    float* out = (float*)d_out;

    const size_t MB = 1024 * 1024;
    char* w = (char*)d_ws;
    ushort* q_b   = (ushort*)(w + 0 * MB);     // 8MB (dead after attn)
    ushort* k_b   = (ushort*)(w + 8 * MB);     // 8MB (dead after attn)
    ushort* vt_b  = (ushort*)(w + 16 * MB);    // 8MB (dead after attn)
    ushort* att_b = (ushort*)(w + 24 * MB);    // 8MB (dead after Wo GEMM)
    ushort* pw    = (ushort*)(w + 32 * MB);    // 32MB Wo split-4 bf16 partials
    ushort* o2_b  = (ushort*)(w + 8 * MB);     // 8MB (over k_b)
    ushort* pf    = (ushort*)(w + 16 * MB);    // 32MB FFN2 split-4 bf16 partials
    ushort* h1_b  = (ushort*)(w + 64 * MB);    // 32MB
    ushort* wq_t  = (ushort*)(w + 96 * MB);    // 2MB (q/k/v/o contiguous slabs)
    ushort* wk_t  = (ushort*)(w + 98 * MB);
    ushort* wv_t  = (ushort*)(w + 100 * MB);
    ushort* wo_t  = (ushort*)(w + 102 * MB);
    ushort* w1_t  = (ushort*)(w + 104 * MB);   // 8MB
    ushort* w2_t  = (ushort*)(w + 112 * MB);   // 8MB
    ushort* xn_b  = (ushort*)(w + 120 * MB);   // 8MB

    // 0. weight convert+transpose (QKVO fused; W1+W2 fused)
    transpose4_bf16_kernel<<<dim3(DD / 32, DD / 32, 4), 256, 0, stream>>>(
        Wq, Wk, Wv, Wo, wq_t);
    transpose_ffn_kernel<<<dim3(FFN / 32, DD / 32, 2), 256, 0, stream>>>(
        W1, W2, w1_t, w2_t);

    // 1. LN1 -> bf16
    ln_kernel<<<NROW, 256, 0, stream>>>(inputs, ln1_scale, ln1_shift, xn_b);

    // 2. Fused QKV projection (N=3072; V transposed per head; q pre-scaled).
    dim3 gqkv(3 * DD / 128, NROW / GBM, 1);   // 24 x 32
    gemm_bf16_kernel<3, true, 3, 128><<<gqkv, 512, 0, stream>>>(
        xn_b, wq_t, bq, nullptr, q_b, NROW, 3 * DD, DD, DD, bk, bv, k_b, vt_b);

    // 3. MFMA flash attention -> att_b (bf16). 512 blocks x 8 waves, 48KB.
    dim3 ga(BB * HH, SS / 128);
    attn_mfma_kernel<<<ga, 512, 0, stream>>>(q_b, k_b, vt_b, att_b);

    // 4. Output projection, split-K=4, BN=256 -> bf16 partials pw.
    dim3 gwo(DD / 256, NROW / GBM, 4);        // 4 x 32 x 4
    gemm_bf16_kernel<4, false, 3, 256><<<gwo, 512, 0, stream>>>(
        att_b, wo_t, nullptr, nullptr, pw, NROW, DD, DD / 4, DD, nullptr, nullptr, nullptr, nullptr);

    // 5. fused reduce(pw)+bias -> +input -> LN2 -> o2 (bf16)
    ln_res4_kernel<<<NROW, 256, 0, stream>>>(pw, bo, inputs, ln2_scale, ln2_shift, o2_b);

    // 6. FFN up + relu -> h1 (bf16). BN=256: 512 blocks at 72KB = 2/CU round.
    dim3 g2(FFN / 256, NROW / GBM, 1);        // 16 x 32
    gemm_bf16_kernel<1, true, 3, 256><<<g2, 512, 0, stream>>>(
        o2_b, w1_t, b1, nullptr, h1_b, NROW, FFN, DD, DD, nullptr, nullptr, nullptr, nullptr);

    // 7. FFN down, split-K=4, BN=256 -> bf16 partials pf. 512 blocks = round.
    dim3 gf2(DD / 256, NROW / GBM, 4);        // 4 x 32 x 4
    gemm_bf16_kernel<4, false, 3, 256><<<gf2, 512, 0, stream>>>(
        h1_b, w2_t, nullptr, nullptr, pf, NROW, DD, FFN / 4, FFN, nullptr, nullptr, nullptr, nullptr);
    reduce_ffn2_kernel<<<(NROW * DD / 4) / 256, 256, 0, stream>>>(pf, b2, o2_b, out);
}